// Round 3
// baseline (450.758 us; speedup 1.0000x reference)
//
#include <hip/hip_runtime.h>
#include <math.h>

#define HW 16384
#define B_ 8
#define C_ 256
#define S_ 64
#define K_ 8

__device__ __forceinline__ float sigmoidf_(float z) { return 1.f / (1.f + __expf(-z)); }

// ---------------- K0: precompute iv = 1/sigma^2, aiv = a*iv, kconst[k] = sum_c a^2*iv ----------------
__global__ __launch_bounds__(256) void k0_prep(const float* __restrict__ anchor,
                                               const float* __restrict__ sigma_p,
                                               float* __restrict__ iv_g, float* __restrict__ aiv_g,
                                               float* __restrict__ kconst) {
    const int c = threadIdx.x;
    const int lane = c & 63, wid = c >> 6;
    __shared__ float red[4][8];
    float kc[8];
#pragma unroll
    for (int k = 0; k < 8; ++k) {
        float sg = sigmoidf_(sigma_p[k * C_ + c]);
        float iv = 1.f / (sg * sg);
        float a = anchor[k * C_ + c];
        iv_g[k * C_ + c] = iv;
        aiv_g[k * C_ + c] = a * iv;
        kc[k] = a * a * iv;
    }
#pragma unroll
    for (int m = 32; m; m >>= 1) {
#pragma unroll
        for (int k = 0; k < 8; ++k) kc[k] += __shfl_xor(kc[k], m, 64);
    }
    if (lane == 0) {
#pragma unroll
        for (int k = 0; k < 8; ++k) red[wid][k] = kc[k];
    }
    __syncthreads();
    if (c < 8) kconst[c] = red[0][c] + red[1][c] + red[2][c] + red[3][c];
}

// ---------------- K1: fused x_proj + d2/softmax(soft) + cm; weights via scalar loads ----------------
__global__ __launch_bounds__(256) void k1_main(
    const float* __restrict__ x, const float* __restrict__ contour,
    const float* __restrict__ wproj, const float* __restrict__ bproj,
    const float* __restrict__ aiv_g, const float* __restrict__ iv_g,
    const float* __restrict__ kconst,
    float* __restrict__ cm, float* __restrict__ xp, float* __restrict__ soft) {
    const int tid = threadIdx.x;
    const int b = blockIdx.y;
    const int n = blockIdx.x * 256 + tid;

    float acc[S_];
    float q1[K_], q2[K_];
#pragma unroll
    for (int s = 0; s < S_; ++s) acc[s] = 0.f;
#pragma unroll
    for (int k = 0; k < K_; ++k) { q1[k] = 0.f; q2[k] = 0.f; }

    const float* xb = x + (size_t)b * C_ * HW + n;
    float xv0 = xb[0], xv1 = xb[HW], xv2 = xb[2 * HW], xv3 = xb[3 * HW];
    for (int c = 0; c < C_; c += 4) {
        int cn = (c + 4 < C_) ? (c + 4) : 0;  // prefetch (wraps harmlessly on last iter)
        const float* p = xb + (size_t)cn * HW;
        float nx0 = p[0], nx1 = p[HW], nx2 = p[2 * HW], nx3 = p[3 * HW];
        // W rows: wave-uniform addresses -> s_load_dwordx4, SGPR operands for FMA
#pragma unroll
        for (int s = 0; s < S_; ++s) {
            const float4 w = *(const float4*)&wproj[s * C_ + c];
            acc[s] = fmaf(w.x, xv0, fmaf(w.y, xv1, fmaf(w.z, xv2, fmaf(w.w, xv3, acc[s]))));
        }
        float x20 = xv0 * xv0, x21 = xv1 * xv1, x22 = xv2 * xv2, x23 = xv3 * xv3;
#pragma unroll
        for (int k = 0; k < K_; ++k) {
            const float4 a = *(const float4*)&aiv_g[k * C_ + c];
            q1[k] = fmaf(a.x, xv0, fmaf(a.y, xv1, fmaf(a.z, xv2, fmaf(a.w, xv3, q1[k]))));
            const float4 v = *(const float4*)&iv_g[k * C_ + c];
            q2[k] = fmaf(v.x, x20, fmaf(v.y, x21, fmaf(v.z, x22, fmaf(v.w, x23, q2[k]))));
        }
        xv0 = nx0; xv1 = nx1; xv2 = nx2; xv3 = nx3;
    }

    // write x_proj (with bias, scalar-loaded)
    float* xpn = xp + (size_t)b * S_ * HW + n;
#pragma unroll
    for (int s = 0; s < S_; ++s) xpn[(size_t)s * HW] = acc[s] + bproj[s];

    // soft = softmax_k(-0.5 * d2)
    float lg[K_], mx = -1e30f;
#pragma unroll
    for (int k = 0; k < K_; ++k) {
        lg[k] = -0.5f * (q2[k] - 2.f * q1[k] + kconst[k]);
        mx = fmaxf(mx, lg[k]);
    }
    float sm = 0.f;
#pragma unroll
    for (int k = 0; k < K_; ++k) { float e = __expf(lg[k] - mx); lg[k] = e; sm += e; }
    float inv = 1.f / sm;
    float* sp = soft + (size_t)b * K_ * HW + n;
#pragma unroll
    for (int k = 0; k < K_; ++k) sp[(size_t)k * HW] = lg[k] * inv;

    // cm = softmax(contour, ch)[1] = sigmoid(c1 - c0)
    float c0 = contour[(size_t)b * 2 * HW + n];
    float c1 = contour[(size_t)b * 2 * HW + HW + n];
    cm[(size_t)b * HW + n] = sigmoidf_(c1 - c0);
}

// ---------------- K2: adaptive-pool cropped bins -> x_anchor (B,64,64) ----------------
__global__ void k2_anchor(const float* __restrict__ xp, const float* __restrict__ cm,
                          float* __restrict__ xa) {
    __shared__ float col[128];
    const int i = blockIdx.x;   // h-bin index (crop): actual bin = i+1
    const int s = blockIdx.y;
    const int b = blockIdx.z;
    const int w = threadIdx.x;  // 0..127
    const int h0 = ((i + 1) * 128) / 10;
    const int h1 = ((i + 2) * 128 + 9) / 10;
    const float* xps = xp + ((size_t)b * S_ + s) * HW;
    const float* cmb = cm + (size_t)b * HW;
    float v = 0.f;
    for (int h = h0; h < h1; ++h) v += xps[h * 128 + w] * cmb[h * 128 + w];
    col[w] = v;
    __syncthreads();
    if (w < 8) {
        const int j = w;
        const int w0 = ((j + 1) * 128) / 10;
        const int w1 = ((j + 2) * 128 + 9) / 10;
        float sum = 0.f;
        for (int t = w0; t < w1; ++t) sum += col[t];
        xa[((size_t)b * S_ + s) * 64 + i * 8 + j] = sum / (float)((h1 - h0) * (w1 - w0));
    }
}

// ---------------- K3: proj = softmax_m( x_anchor^T(s,m) . x_proj(s,n) ), in place ----------------
// x_anchor rows read as wave-uniform scalar loads (no LDS).
__global__ __launch_bounds__(256) void k3_proj(const float* __restrict__ xa, float* __restrict__ xp) {
    const int b = blockIdx.y, tid = threadIdx.x;
    const int n = blockIdx.x * 256 + tid;
    const float* xab = xa + (size_t)b * 4096;
    float p[64];
#pragma unroll
    for (int m = 0; m < 64; ++m) p[m] = 0.f;
    float* xpb = xp + (size_t)b * S_ * HW + n;
    float xv = xpb[0];
    for (int s = 0; s < 64; ++s) {
        float xnext = (s < 63) ? xpb[(size_t)(s + 1) * HW] : 0.f;
#pragma unroll
        for (int m = 0; m < 64; m += 4) {
            const float4 a = *(const float4*)&xab[s * 64 + m];
            p[m] = fmaf(a.x, xv, p[m]);
            p[m + 1] = fmaf(a.y, xv, p[m + 1]);
            p[m + 2] = fmaf(a.z, xv, p[m + 2]);
            p[m + 3] = fmaf(a.w, xv, p[m + 3]);
        }
        xv = xnext;
    }
    float mx = -1e30f;
#pragma unroll
    for (int m = 0; m < 64; ++m) mx = fmaxf(mx, p[m]);
    float sm = 0.f;
#pragma unroll
    for (int m = 0; m < 64; ++m) { float e = __expf(p[m] - mx); p[m] = e; sm += e; }
    float inv = 1.f / sm;
#pragma unroll
    for (int m = 0; m < 64; ++m) xpb[(size_t)m * HW] = p[m] * inv;
}

// ---------------- K4: ssum[b,k] = sum_n soft[b,k,n] ----------------
__global__ __launch_bounds__(256) void k4_ssum(const float* __restrict__ soft,
                                               float* __restrict__ ssumg) {
    const int bk = blockIdx.x;  // 0..63
    const int tid = threadIdx.x;
    const float4* sp = (const float4*)(soft + (size_t)bk * HW);
    float v = 0.f;
    for (int i = tid; i < HW / 4; i += 256) {
        float4 t = sp[i];
        v += (t.x + t.y) + (t.z + t.w);
    }
#pragma unroll
    for (int m = 32; m; m >>= 1) v += __shfl_xor(v, m, 64);
    __shared__ float red[4];
    const int wid = tid >> 6, lane = tid & 63;
    if (lane == 0) red[wid] = v;
    __syncthreads();
    if (tid == 0) ssumg[bk] = red[0] + red[1] + red[2] + red[3];
}

// ---------------- K5: wsum[b,k,c] = sum_n soft[b,k,n] * x[b,c,n] (float4) ----------------
__global__ __launch_bounds__(256) void k5_wsum(const float* __restrict__ x,
                                               const float* __restrict__ soft,
                                               float* __restrict__ wsum) {
    const int b = blockIdx.y;
    const int c0 = blockIdx.x * 4;
    const int tid = threadIdx.x;
    float a[32];
#pragma unroll
    for (int i = 0; i < 32; ++i) a[i] = 0.f;
    const float4* sb = (const float4*)(soft + (size_t)b * K_ * HW);
    const float4* xb = (const float4*)(x + ((size_t)b * C_ + c0) * HW);
    for (int i = tid; i < HW / 4; i += 256) {
        float4 sv[8];
#pragma unroll
        for (int k = 0; k < 8; ++k) sv[k] = sb[(size_t)k * (HW / 4) + i];
#pragma unroll
        for (int ci = 0; ci < 4; ++ci) {
            float4 xv = xb[(size_t)ci * (HW / 4) + i];
#pragma unroll
            for (int k = 0; k < 8; ++k) {
                float t = fmaf(sv[k].x, xv.x, fmaf(sv[k].y, xv.y,
                          fmaf(sv[k].z, xv.z, sv[k].w * xv.w)));
                a[ci * 8 + k] += t;
            }
        }
    }
    __shared__ float red[128];
    const int lane = tid & 63, wid = tid >> 6;
#pragma unroll
    for (int o = 0; o < 32; ++o) {
        float v = a[o];
#pragma unroll
        for (int m = 32; m; m >>= 1) v += __shfl_xor(v, m, 64);
        if (lane == 0) red[wid * 32 + o] = v;
    }
    __syncthreads();
    if (tid < 32) {
        float r = red[tid] + red[32 + tid] + red[64 + tid] + red[96 + tid];
        int ci = tid >> 3, k = tid & 7;
        wsum[((size_t)b * K_ + k) * C_ + c0 + ci] = r;
    }
}

// ---------------- K6: nodes, normalize, 3x GCN, relu -> g ----------------
__device__ __forceinline__ float blockSum256(float v, volatile float* sc) {
#pragma unroll
    for (int m = 32; m; m >>= 1) v += __shfl_xor(v, m, 64);
    const int wid = threadIdx.x >> 6, lane = threadIdx.x & 63;
    __syncthreads();
    if (lane == 0) sc[wid] = v;
    __syncthreads();
    return sc[0] + sc[1] + sc[2] + sc[3];
}

__global__ __launch_bounds__(256) void k6_gcn(const float* __restrict__ ssumg,
                                              const float* __restrict__ wsum,
                                              const float* __restrict__ anchor,
                                              const float* __restrict__ sigma_p,
                                              const float* __restrict__ w1,
                                              const float* __restrict__ w2,
                                              const float* __restrict__ w3,
                                              float* __restrict__ gout) {
    const int b = blockIdx.x;
    const int tid = threadIdx.x;
    const int lane = tid & 63, wid = tid >> 6;
    __shared__ float g_lds[2048];  // g[c][k] at [c*8+k]  (== flat[k*256+c] view)
    __shared__ float A[64];
    __shared__ float sc[4];
    __shared__ float red8[4][8];
    __shared__ float ssk_s[8];

    if (tid < 8) ssk_s[tid] = ssumg[b * 8 + tid];
    __syncthreads();
    float ssk[8];
#pragma unroll
    for (int k = 0; k < 8; ++k) ssk[k] = ssk_s[k];

    // nodes (thread = channel c)
    const int c = tid;
    float node[8];
#pragma unroll
    for (int k = 0; k < 8; ++k) {
        float sg = sigmoidf_(sigma_p[k * C_ + c]);
        float w = wsum[((size_t)b * K_ + k) * C_ + c];
        node[k] = (w - anchor[k * C_ + c] * ssk[k]) / sg / (ssk[k] + 1e-9f);
    }
    // batched row-norm reduction: rn[k] = sum_c node[k]^2
    float rn[8];
#pragma unroll
    for (int k = 0; k < 8; ++k) rn[k] = node[k] * node[k];
#pragma unroll
    for (int m = 32; m; m >>= 1) {
#pragma unroll
        for (int k = 0; k < 8; ++k) rn[k] += __shfl_xor(rn[k], m, 64);
    }
    if (lane == 0) {
#pragma unroll
        for (int k = 0; k < 8; ++k) red8[wid][k] = rn[k];
    }
    __syncthreads();
#pragma unroll
    for (int k = 0; k < 8; ++k) {
        float t = red8[0][k] + red8[1][k] + red8[2][k] + red8[3][k];
        node[k] /= fmaxf(sqrtf(t), 1e-12f);
    }
    float fs = 0.f;
#pragma unroll
    for (int k = 0; k < 8; ++k) fs += node[k] * node[k];
    float fn = blockSum256(fs, sc);
    float finv = 1.f / fmaxf(sqrtf(fn), 1e-12f);
#pragma unroll
    for (int k = 0; k < 8; ++k) g_lds[tid * 8 + k] = node[k] * finv;  // g[c][k], c=tid
    __syncthreads();

    const float* Ws[3] = {w1, w2, w3};
    for (int L = 0; L < 3; ++L) {
        // A[p][q] = sum_i g[i][p] g[i][q], 4 threads per (p,q) pair
        {
            const int pair = tid >> 2, part = tid & 3;  // pair 0..63
            const int p = pair >> 3, q = pair & 7;
            float s = 0.f;
            for (int i = part * 64; i < part * 64 + 64; ++i)
                s += g_lds[i * 8 + p] * g_lds[i * 8 + q];
            s += __shfl_xor(s, 1, 64);
            s += __shfl_xor(s, 2, 64);
            if (part == 0) A[pair] = s;
        }
        __syncthreads();
        if (tid < 8) {  // row softmax
            float mx = -1e30f;
            for (int j = 0; j < 8; ++j) mx = fmaxf(mx, A[tid * 8 + j]);
            float sm = 0.f;
            for (int j = 0; j < 8; ++j) { float e = __expf(A[tid * 8 + j] - mx); A[tid * 8 + j] = e; sm += e; }
            float iv = 1.f / sm;
            for (int j = 0; j < 8; ++j) A[tid * 8 + j] *= iv;
        }
        __syncthreads();
        // support[j][d=tid] = sum_c g[c][j] * W[c][d] — W direct global->reg, double-buffered
        float sup[8];
#pragma unroll
        for (int j = 0; j < 8; ++j) sup[j] = 0.f;
        const float* W = Ws[L];
        float wv[8], wn[8];
#pragma unroll
        for (int i = 0; i < 8; ++i) wv[i] = W[(size_t)i * 256 + tid];
        for (int c0 = 0; c0 < 256; c0 += 8) {
            if (c0 + 8 < 256) {
#pragma unroll
                for (int i = 0; i < 8; ++i) wn[i] = W[(size_t)(c0 + 8 + i) * 256 + tid];
            }
#pragma unroll
            for (int i = 0; i < 8; ++i) {
#pragma unroll
                for (int j = 0; j < 8; ++j)
                    sup[j] = fmaf(g_lds[(c0 + i) * 8 + j], wv[i], sup[j]);
            }
#pragma unroll
            for (int i = 0; i < 8; ++i) wv[i] = wn[i];
        }
        // g_new[d][k] = sum_j adj[k][j] * support[j][d]
        float gn[8];
#pragma unroll
        for (int k = 0; k < 8; ++k) {
            float s = 0.f;
#pragma unroll
            for (int j = 0; j < 8; ++j) s += A[k * 8 + j] * sup[j];
            gn[k] = s;
        }
        __syncthreads();
#pragma unroll
        for (int k = 0; k < 8; ++k) g_lds[tid * 8 + k] = gn[k];
        __syncthreads();
    }
#pragma unroll
    for (int k = 0; k < 8; ++k)
        gout[(size_t)b * 2048 + tid * 8 + k] = fmaxf(g_lds[tid * 8 + k], 0.f);
}

extern "C" void kernel_launch(void* const* d_in, const int* in_sizes, int n_in,
                              void* d_out, int out_size, void* d_ws, size_t ws_size,
                              hipStream_t stream) {
    const float* x = (const float*)d_in[0];
    const float* contour = (const float*)d_in[1];
    const float* wproj = (const float*)d_in[4];
    const float* bproj = (const float*)d_in[5];
    const float* anchor = (const float*)d_in[6];
    const float* sigma_p = (const float*)d_in[7];
    const float* w1 = (const float*)d_in[8];
    const float* w2 = (const float*)d_in[9];
    const float* w3 = (const float*)d_in[10];

    float* out = (float*)d_out;
    float* g_out = out;                        // (B,256,8)
    float* xp = out + 16384;                   // proj region (B,64,HW): x_proj, then proj in-place
    float* soft = out + 16384 + 8388608;       // (B,8,HW)

    float* ws = (float*)d_ws;
    float* cm = ws;                 // B*HW = 131072
    float* xa = ws + 131072;        // B*64*64 = 32768
    float* wsum = ws + 163840;      // B*8*256 = 16384
    float* kconst = ws + 180224;    // 8
    float* ssumg = ws + 180232;     // 64
    float* iv_g = ws + 180296;      // 2048
    float* aiv_g = ws + 182344;     // 2048

    k0_prep<<<1, 256, 0, stream>>>(anchor, sigma_p, iv_g, aiv_g, kconst);
    k1_main<<<dim3(64, B_), 256, 0, stream>>>(x, contour, wproj, bproj, aiv_g, iv_g,
                                              kconst, cm, xp, soft);
    k4_ssum<<<B_ * K_, 256, 0, stream>>>(soft, ssumg);
    k2_anchor<<<dim3(8, 64, B_), 128, 0, stream>>>(xp, cm, xa);
    k3_proj<<<dim3(64, B_), 256, 0, stream>>>(xa, xp);
    k5_wsum<<<dim3(64, B_), 256, 0, stream>>>(x, soft, wsum);
    k6_gcn<<<B_, 256, 0, stream>>>(ssumg, wsum, anchor, sigma_p, w1, w2, w3, g_out);
}

// Round 4
// 311.383 us; speedup vs baseline: 1.4476x; 1.4476x over previous
//
#include <hip/hip_runtime.h>
#include <math.h>

#define HW 16384
#define B_ 8
#define C_ 256
#define S_ 64
#define K_ 8

__device__ __forceinline__ float sigmoidf_(float z) { return 1.f / (1.f + __expf(-z)); }

// ---------------- K0: precompute iv, aiv, kconst, and Wt[c][s] = wproj[s][c] ----------------
__global__ __launch_bounds__(256) void k0_prep(const float* __restrict__ anchor,
                                               const float* __restrict__ sigma_p,
                                               const float* __restrict__ wproj,
                                               float* __restrict__ iv_g, float* __restrict__ aiv_g,
                                               float* __restrict__ kconst, float* __restrict__ Wt) {
    const int c = threadIdx.x;
    const int lane = c & 63, wid = c >> 6;
    __shared__ float red[4][8];
    float kc[8];
#pragma unroll
    for (int k = 0; k < 8; ++k) {
        float sg = sigmoidf_(sigma_p[k * C_ + c]);
        float iv = 1.f / (sg * sg);
        float a = anchor[k * C_ + c];
        iv_g[k * C_ + c] = iv;
        aiv_g[k * C_ + c] = a * iv;
        kc[k] = a * a * iv;
    }
    for (int s = 0; s < S_; ++s) Wt[c * S_ + s] = wproj[s * C_ + c];
#pragma unroll
    for (int m = 32; m; m >>= 1) {
#pragma unroll
        for (int k = 0; k < 8; ++k) kc[k] += __shfl_xor(kc[k], m, 64);
    }
    if (lane == 0) {
#pragma unroll
        for (int k = 0; k < 8; ++k) red[wid][k] = kc[k];
    }
    __syncthreads();
    if (c < 8) kconst[c] = red[0][c] + red[1][c] + red[2][c] + red[3][c];
}

// ---------------- K1a: x_proj GEMM, lane = s-row, x via wave-uniform scalar loads ----------------
__global__ __launch_bounds__(256) void k1a_proj(const float* __restrict__ x,
                                                const float* __restrict__ Wt,
                                                const float* __restrict__ bproj,
                                                float* __restrict__ xp) {
    const int tid = threadIdx.x;
    const int lane = tid & 63;   // s index
    const int wv = tid >> 6;
    const int b = blockIdx.y;
    const int px0 = __builtin_amdgcn_readfirstlane(blockIdx.x * 64 + wv * 16);
    const float* xb = x + (size_t)b * C_ * HW + px0;   // wave-uniform base
    const float* wt = Wt + lane;

    float acc[16];
#pragma unroll
    for (int p = 0; p < 16; ++p) acc[p] = 0.f;

#pragma unroll 4
    for (int c = 0; c < C_; ++c) {
        float wv_ = wt[(size_t)c * S_];            // per-lane coalesced dword
        const float* xr = xb + (size_t)c * HW;     // uniform -> s_load
#pragma unroll
        for (int p = 0; p < 16; ++p) acc[p] = fmaf(wv_, xr[p], acc[p]);
    }

    const float bias = bproj[lane];
    float* o = xp + ((size_t)b * S_ + lane) * HW + px0;
#pragma unroll
    for (int p = 0; p < 16; ++p) o[p] = acc[p] + bias;
}

// ---------------- K1b: d2 -> soft (fp32) + cm, 2 px/thread (float2) ----------------
__device__ __forceinline__ void fma2_(float s, const float2& v, float2& a) {
    a.x = fmaf(s, v.x, a.x);
    a.y = fmaf(s, v.y, a.y);
}

__global__ __launch_bounds__(256) void k1b_soft(const float* __restrict__ x,
                                                const float* __restrict__ contour,
                                                const float* __restrict__ aiv_g,
                                                const float* __restrict__ iv_g,
                                                const float* __restrict__ kconst,
                                                float* __restrict__ cm, float* __restrict__ soft) {
    __shared__ float aivl[K_ * C_];  // 8 KB
    __shared__ float ivl[K_ * C_];   // 8 KB
    const int tid = threadIdx.x;
    const int b = blockIdx.y;
    const int n = blockIdx.x * 512 + tid * 2;

    {
        const float4* a4 = (const float4*)aiv_g;
        const float4* i4 = (const float4*)iv_g;
        float4* al = (float4*)aivl;
        float4* il = (float4*)ivl;
        for (int i = tid; i < K_ * C_ / 4; i += 256) { al[i] = a4[i]; il[i] = i4[i]; }
    }
    __syncthreads();

    float2 q1[K_], q2[K_];
#pragma unroll
    for (int k = 0; k < K_; ++k) { q1[k] = make_float2(0.f, 0.f); q2[k] = make_float2(0.f, 0.f); }

    const float* xbase = x + (size_t)b * C_ * HW + n;
    float2 xv[4];
#pragma unroll
    for (int j = 0; j < 4; ++j) xv[j] = *(const float2*)(xbase + (size_t)j * HW);

    for (int c = 0; c < C_; c += 4) {
        const int cn = (c + 4 < C_) ? (c + 4) : 0;
        float2 nx[4];
#pragma unroll
        for (int j = 0; j < 4; ++j) nx[j] = *(const float2*)(xbase + (size_t)(cn + j) * HW);
        float2 x2[4];
#pragma unroll
        for (int j = 0; j < 4; ++j) { x2[j].x = xv[j].x * xv[j].x; x2[j].y = xv[j].y * xv[j].y; }
#pragma unroll
        for (int k = 0; k < K_; ++k) {
            const float4 a = *(const float4*)&aivl[k * C_ + c];
            fma2_(a.x, xv[0], q1[k]); fma2_(a.y, xv[1], q1[k]);
            fma2_(a.z, xv[2], q1[k]); fma2_(a.w, xv[3], q1[k]);
            const float4 v = *(const float4*)&ivl[k * C_ + c];
            fma2_(v.x, x2[0], q2[k]); fma2_(v.y, x2[1], q2[k]);
            fma2_(v.z, x2[2], q2[k]); fma2_(v.w, x2[3], q2[k]);
        }
#pragma unroll
        for (int j = 0; j < 4; ++j) xv[j] = nx[j];
    }

    // softmax over k, per component
    float2 lg[K_];
    float2 mx = make_float2(-1e30f, -1e30f);
#pragma unroll
    for (int k = 0; k < K_; ++k) {
        float kc = kconst[k];
        lg[k].x = -0.5f * (q2[k].x - 2.f * q1[k].x + kc);
        lg[k].y = -0.5f * (q2[k].y - 2.f * q1[k].y + kc);
        mx.x = fmaxf(mx.x, lg[k].x);
        mx.y = fmaxf(mx.y, lg[k].y);
    }
    float2 sm = make_float2(0.f, 0.f);
#pragma unroll
    for (int k = 0; k < K_; ++k) {
        lg[k].x = __expf(lg[k].x - mx.x);
        lg[k].y = __expf(lg[k].y - mx.y);
        sm.x += lg[k].x; sm.y += lg[k].y;
    }
    const float ix = 1.f / sm.x, iy = 1.f / sm.y;
    float* sp = soft + (size_t)b * K_ * HW + n;
#pragma unroll
    for (int k = 0; k < K_; ++k) {
        float2 o; o.x = lg[k].x * ix; o.y = lg[k].y * iy;
        *(float2*)(sp + (size_t)k * HW) = o;
    }

    // cm = sigmoid(c1 - c0)
    const float2 c0 = *(const float2*)(contour + (size_t)b * 2 * HW + n);
    const float2 c1 = *(const float2*)(contour + (size_t)b * 2 * HW + HW + n);
    float2 cmv; cmv.x = sigmoidf_(c1.x - c0.x); cmv.y = sigmoidf_(c1.y - c0.y);
    *(float2*)(cm + (size_t)b * HW + n) = cmv;
}

// ---------------- K2: adaptive-pool cropped bins -> x_anchor (B,64,64) ----------------
__global__ void k2_anchor(const float* __restrict__ xp, const float* __restrict__ cm,
                          float* __restrict__ xa) {
    __shared__ float col[128];
    const int i = blockIdx.x;
    const int s = blockIdx.y;
    const int b = blockIdx.z;
    const int w = threadIdx.x;
    const int h0 = ((i + 1) * 128) / 10;
    const int h1 = ((i + 2) * 128 + 9) / 10;
    const float* xps = xp + ((size_t)b * S_ + s) * HW;
    const float* cmb = cm + (size_t)b * HW;
    float v = 0.f;
    for (int h = h0; h < h1; ++h) v += xps[h * 128 + w] * cmb[h * 128 + w];
    col[w] = v;
    __syncthreads();
    if (w < 8) {
        const int j = w;
        const int w0 = ((j + 1) * 128) / 10;
        const int w1 = ((j + 2) * 128 + 9) / 10;
        float sum = 0.f;
        for (int t = w0; t < w1; ++t) sum += col[t];
        xa[((size_t)b * S_ + s) * 64 + i * 8 + j] = sum / (float)((h1 - h0) * (w1 - w0));
    }
}

// ---------------- K3: proj = softmax_m( x_anchor^T . x_proj ), in place ----------------
__global__ __launch_bounds__(256) void k3_proj(const float* __restrict__ xa, float* __restrict__ xp) {
    const int b = blockIdx.y, tid = threadIdx.x;
    const int n = blockIdx.x * 256 + tid;
    const float* xab = xa + (size_t)b * 4096;
    float p[64];
#pragma unroll
    for (int m = 0; m < 64; ++m) p[m] = 0.f;
    float* xpb = xp + (size_t)b * S_ * HW + n;
    float xv = xpb[0];
    for (int s = 0; s < 64; ++s) {
        float xnext = (s < 63) ? xpb[(size_t)(s + 1) * HW] : 0.f;
#pragma unroll
        for (int m = 0; m < 64; m += 4) {
            const float4 a = *(const float4*)&xab[s * 64 + m];
            p[m] = fmaf(a.x, xv, p[m]);
            p[m + 1] = fmaf(a.y, xv, p[m + 1]);
            p[m + 2] = fmaf(a.z, xv, p[m + 2]);
            p[m + 3] = fmaf(a.w, xv, p[m + 3]);
        }
        xv = xnext;
    }
    float mx = -1e30f;
#pragma unroll
    for (int m = 0; m < 64; ++m) mx = fmaxf(mx, p[m]);
    float sm = 0.f;
#pragma unroll
    for (int m = 0; m < 64; ++m) { float e = __expf(p[m] - mx); p[m] = e; sm += e; }
    float inv = 1.f / sm;
#pragma unroll
    for (int m = 0; m < 64; ++m) xpb[(size_t)m * HW] = p[m] * inv;
}

// ---------------- K4: ssum[b,k] = sum_n soft[b,k,n] ----------------
__global__ __launch_bounds__(256) void k4_ssum(const float* __restrict__ soft,
                                               float* __restrict__ ssumg) {
    const int bk = blockIdx.x;
    const int tid = threadIdx.x;
    const float4* sp = (const float4*)(soft + (size_t)bk * HW);
    float v = 0.f;
    for (int i = tid; i < HW / 4; i += 256) {
        float4 t = sp[i];
        v += (t.x + t.y) + (t.z + t.w);
    }
#pragma unroll
    for (int m = 32; m; m >>= 1) v += __shfl_xor(v, m, 64);
    __shared__ float red[4];
    const int wid = tid >> 6, lane = tid & 63;
    if (lane == 0) red[wid] = v;
    __syncthreads();
    if (tid == 0) ssumg[bk] = red[0] + red[1] + red[2] + red[3];
}

// ---------------- K5: wsum[b,k,c] = sum_n soft[b,k,n] * x[b,c,n] (float4) ----------------
__global__ __launch_bounds__(256) void k5_wsum(const float* __restrict__ x,
                                               const float* __restrict__ soft,
                                               float* __restrict__ wsum) {
    const int b = blockIdx.y;
    const int c0 = blockIdx.x * 4;
    const int tid = threadIdx.x;
    float a[32];
#pragma unroll
    for (int i = 0; i < 32; ++i) a[i] = 0.f;
    const float4* sb = (const float4*)(soft + (size_t)b * K_ * HW);
    const float4* xb = (const float4*)(x + ((size_t)b * C_ + c0) * HW);
    for (int i = tid; i < HW / 4; i += 256) {
        float4 sv[8];
#pragma unroll
        for (int k = 0; k < 8; ++k) sv[k] = sb[(size_t)k * (HW / 4) + i];
#pragma unroll
        for (int ci = 0; ci < 4; ++ci) {
            float4 xv = xb[(size_t)ci * (HW / 4) + i];
#pragma unroll
            for (int k = 0; k < 8; ++k) {
                float t = fmaf(sv[k].x, xv.x, fmaf(sv[k].y, xv.y,
                          fmaf(sv[k].z, xv.z, sv[k].w * xv.w)));
                a[ci * 8 + k] += t;
            }
        }
    }
    __shared__ float red[128];
    const int lane = tid & 63, wid = tid >> 6;
#pragma unroll
    for (int o = 0; o < 32; ++o) {
        float v = a[o];
#pragma unroll
        for (int m = 32; m; m >>= 1) v += __shfl_xor(v, m, 64);
        if (lane == 0) red[wid * 32 + o] = v;
    }
    __syncthreads();
    if (tid < 32) {
        float r = red[tid] + red[32 + tid] + red[64 + tid] + red[96 + tid];
        int ci = tid >> 3, k = tid & 7;
        wsum[((size_t)b * K_ + k) * C_ + c0 + ci] = r;
    }
}

// ---------------- K6: nodes, normalize, 3x GCN, relu -> g ----------------
__device__ __forceinline__ float blockSum256(float v, volatile float* sc) {
#pragma unroll
    for (int m = 32; m; m >>= 1) v += __shfl_xor(v, m, 64);
    const int wid = threadIdx.x >> 6, lane = threadIdx.x & 63;
    __syncthreads();
    if (lane == 0) sc[wid] = v;
    __syncthreads();
    return sc[0] + sc[1] + sc[2] + sc[3];
}

__global__ __launch_bounds__(256) void k6_gcn(const float* __restrict__ ssumg,
                                              const float* __restrict__ wsum,
                                              const float* __restrict__ anchor,
                                              const float* __restrict__ sigma_p,
                                              const float* __restrict__ w1,
                                              const float* __restrict__ w2,
                                              const float* __restrict__ w3,
                                              float* __restrict__ gout) {
    const int b = blockIdx.x;
    const int tid = threadIdx.x;
    const int lane = tid & 63, wid = tid >> 6;
    __shared__ float g_lds[2048];
    __shared__ float A[64];
    __shared__ float sc[4];
    __shared__ float red8[4][8];
    __shared__ float ssk_s[8];

    if (tid < 8) ssk_s[tid] = ssumg[b * 8 + tid];
    __syncthreads();
    float ssk[8];
#pragma unroll
    for (int k = 0; k < 8; ++k) ssk[k] = ssk_s[k];

    const int c = tid;
    float node[8];
#pragma unroll
    for (int k = 0; k < 8; ++k) {
        float sg = sigmoidf_(sigma_p[k * C_ + c]);
        float w = wsum[((size_t)b * K_ + k) * C_ + c];
        node[k] = (w - anchor[k * C_ + c] * ssk[k]) / sg / (ssk[k] + 1e-9f);
    }
    float rn[8];
#pragma unroll
    for (int k = 0; k < 8; ++k) rn[k] = node[k] * node[k];
#pragma unroll
    for (int m = 32; m; m >>= 1) {
#pragma unroll
        for (int k = 0; k < 8; ++k) rn[k] += __shfl_xor(rn[k], m, 64);
    }
    if (lane == 0) {
#pragma unroll
        for (int k = 0; k < 8; ++k) red8[wid][k] = rn[k];
    }
    __syncthreads();
#pragma unroll
    for (int k = 0; k < 8; ++k) {
        float t = red8[0][k] + red8[1][k] + red8[2][k] + red8[3][k];
        node[k] /= fmaxf(sqrtf(t), 1e-12f);
    }
    float fs = 0.f;
#pragma unroll
    for (int k = 0; k < 8; ++k) fs += node[k] * node[k];
    float fn = blockSum256(fs, sc);
    float finv = 1.f / fmaxf(sqrtf(fn), 1e-12f);
#pragma unroll
    for (int k = 0; k < 8; ++k) g_lds[tid * 8 + k] = node[k] * finv;
    __syncthreads();

    const float* Ws[3] = {w1, w2, w3};
    for (int L = 0; L < 3; ++L) {
        {
            const int pair = tid >> 2, part = tid & 3;
            const int p = pair >> 3, q = pair & 7;
            float s = 0.f;
            for (int i = part * 64; i < part * 64 + 64; ++i)
                s += g_lds[i * 8 + p] * g_lds[i * 8 + q];
            s += __shfl_xor(s, 1, 64);
            s += __shfl_xor(s, 2, 64);
            if (part == 0) A[pair] = s;
        }
        __syncthreads();
        if (tid < 8) {
            float mx = -1e30f;
            for (int j = 0; j < 8; ++j) mx = fmaxf(mx, A[tid * 8 + j]);
            float sm = 0.f;
            for (int j = 0; j < 8; ++j) { float e = __expf(A[tid * 8 + j] - mx); A[tid * 8 + j] = e; sm += e; }
            float iv = 1.f / sm;
            for (int j = 0; j < 8; ++j) A[tid * 8 + j] *= iv;
        }
        __syncthreads();
        float sup[8];
#pragma unroll
        for (int j = 0; j < 8; ++j) sup[j] = 0.f;
        const float* W = Ws[L];
        float wv[8], wn[8];
#pragma unroll
        for (int i = 0; i < 8; ++i) wv[i] = W[(size_t)i * 256 + tid];
        for (int c0 = 0; c0 < 256; c0 += 8) {
            if (c0 + 8 < 256) {
#pragma unroll
                for (int i = 0; i < 8; ++i) wn[i] = W[(size_t)(c0 + 8 + i) * 256 + tid];
            }
#pragma unroll
            for (int i = 0; i < 8; ++i) {
#pragma unroll
                for (int j = 0; j < 8; ++j)
                    sup[j] = fmaf(g_lds[(c0 + i) * 8 + j], wv[i], sup[j]);
            }
#pragma unroll
            for (int i = 0; i < 8; ++i) wv[i] = wn[i];
        }
        float gn[8];
#pragma unroll
        for (int k = 0; k < 8; ++k) {
            float s = 0.f;
#pragma unroll
            for (int j = 0; j < 8; ++j) s += A[k * 8 + j] * sup[j];
            gn[k] = s;
        }
        __syncthreads();
#pragma unroll
        for (int k = 0; k < 8; ++k) g_lds[tid * 8 + k] = gn[k];
        __syncthreads();
    }
#pragma unroll
    for (int k = 0; k < 8; ++k)
        gout[(size_t)b * 2048 + tid * 8 + k] = fmaxf(g_lds[tid * 8 + k], 0.f);
}

extern "C" void kernel_launch(void* const* d_in, const int* in_sizes, int n_in,
                              void* d_out, int out_size, void* d_ws, size_t ws_size,
                              hipStream_t stream) {
    const float* x = (const float*)d_in[0];
    const float* contour = (const float*)d_in[1];
    const float* wproj = (const float*)d_in[4];
    const float* bproj = (const float*)d_in[5];
    const float* anchor = (const float*)d_in[6];
    const float* sigma_p = (const float*)d_in[7];
    const float* w1 = (const float*)d_in[8];
    const float* w2 = (const float*)d_in[9];
    const float* w3 = (const float*)d_in[10];

    float* out = (float*)d_out;
    float* g_out = out;                        // (B,256,8)
    float* xp = out + 16384;                   // proj region (B,64,HW)
    float* soft = out + 16384 + 8388608;       // (B,8,HW)

    float* ws = (float*)d_ws;
    float* cm = ws;                 // B*HW = 131072
    float* xa = ws + 131072;        // 32768
    float* wsum = ws + 163840;      // 16384
    float* kconst = ws + 180224;    // 8
    float* ssumg = ws + 180232;     // 64
    float* iv_g = ws + 180296;      // 2048
    float* aiv_g = ws + 182344;     // 2048
    float* Wt = ws + 184392;        // 16384

    k0_prep<<<1, 256, 0, stream>>>(anchor, sigma_p, wproj, iv_g, aiv_g, kconst, Wt);
    k1a_proj<<<dim3(HW / 64, B_), 256, 0, stream>>>(x, Wt, bproj, xp);
    k1b_soft<<<dim3(HW / 512, B_), 256, 0, stream>>>(x, contour, aiv_g, iv_g, kconst, cm, soft);
    k4_ssum<<<B_ * K_, 256, 0, stream>>>(soft, ssumg);
    k2_anchor<<<dim3(8, 64, B_), 128, 0, stream>>>(xp, cm, xa);
    k3_proj<<<dim3(64, B_), 256, 0, stream>>>(xa, xp);
    k5_wsum<<<dim3(64, B_), 256, 0, stream>>>(x, soft, wsum);
    k6_gcn<<<B_, 256, 0, stream>>>(ssumg, wsum, anchor, sigma_p, w1, w2, w3, g_out);
}